// Round 3
// baseline (655.016 us; speedup 1.0000x reference)
//
#include <hip/hip_runtime.h>
#include <cstdint>
#include <cstddef>

typedef _Float16 f16;
typedef _Float16 f16x8 __attribute__((ext_vector_type(8)));
typedef float f32x4 __attribute__((ext_vector_type(4)));

// ---------------------------------------------------------------------------
// W is stored fragment-tiled for mfma_f32_16x16x32_f16's B operand:
// lane l of a wave holds B[n = nf*16 + (l&15)][k = kb*32 + (l>>4)*8 + j].
// Element (n,k) lives at flat f16 index
//   ((n>>4)*(K/32) + (k>>5))*512 + (((k>>3)&3)*16 + (n&15))*8 + (k&7)
// so a wave loads one fragment as ONE coalesced global_load_dwordx4.
// ---------------------------------------------------------------------------

// Wt tile for coef: k = i*8+g  ->  kb=i>>2, lane=(i&3)*16+(o&15), elem g
template <int I, int O>
__global__ void prep_coef(const float* __restrict__ coef,
                          const float* __restrict__ ssp,
                          f16* __restrict__ Wt) {
  constexpr int K32 = (9 * I) / 32;
  int tid = blockIdx.x * 256 + threadIdx.x;
  if (tid >= I * O) return;
  int i = tid / O, o = tid % O;             // o fastest -> coalesced coef reads
  float s = ssp[tid];
  const float* c = coef + (size_t)tid * 8;
  f16x8 out;
#pragma unroll
  for (int g = 0; g < 8; ++g) out[g] = (f16)(c[g] * s);
  size_t addr = ((size_t)(o >> 4) * K32 + (i >> 2)) * 512 +
                (size_t)(((i & 3) * 16) + (o & 15)) * 8;
  *(f16x8*)(Wt + addr) = out;
}

// Wt tile for base: k = 8I+i -> kb=I/4+(i>>5), lane=((i>>3)&3)*16+(o&15), elem i&7
template <int I, int O>
__global__ void prep_base(const float* __restrict__ sb, f16* __restrict__ Wt) {
  constexpr int K32 = (9 * I) / 32;
  int tid = blockIdx.x * 256 + threadIdx.x;
  if (tid >= (I / 8) * O) return;
  int i8 = tid / O, o = tid % O;            // o fastest -> coalesced writes
  f16x8 out;
#pragma unroll
  for (int s = 0; s < 8; ++s)
    out[s] = (f16)sb[(size_t)(i8 * 8 + s) * O + o];
  size_t addr = ((size_t)(o >> 4) * K32 + (I / 4) + (i8 >> 2)) * 512 +
                (size_t)(((i8 & 3) * 16) + (o & 15)) * 8;
  *(f16x8*)(Wt + addr) = out;
}

// ---------------------------------------------------------------------------
// 8-slot cubic B-spline basis, packed-shift form (verified R6, absmax 0.0625).
// ---------------------------------------------------------------------------
__device__ __forceinline__ f16x8 spline8(float h) {
  float v = __builtin_fmaf(2.5f, h, 5.5f);
  float c = floorf(v);
  float f = v - c;
  float f2 = f * f, f3 = f2 * f;
  float b3 = f3 * (1.f / 6.f);
  float t = 1.f - f;
  float b0 = t * t * t * (1.f / 6.f);
  float b1 = (2.f / 3.f) - f2 + 0.5f * f3;
  float b2 = 1.f - b0 - b1 - b3;
  unsigned int u01 =
      __builtin_bit_cast(unsigned int, __builtin_amdgcn_cvt_pkrtz(b0, b1));
  unsigned int u23 =
      __builtin_bit_cast(unsigned int, __builtin_amdgcn_cvt_pkrtz(b2, b3));
  unsigned long long pk = (unsigned long long)u01 |
                          ((unsigned long long)u23 << 32);
  int ci = (int)c;
  int s = (ci - 3) * 16;                // bit offset of slot c-3
  __uint128_t r = 0;
  if (s >= 0) {
    if (s < 128) r = (__uint128_t)pk << s;
  } else {
    int q = -s;
    if (q < 64) r = (__uint128_t)(pk >> q);
  }
  return __builtin_bit_cast(f16x8, r);
}

// ---------------------------------------------------------------------------
// Fused KAN GEMM. R9: OCCUPANCY restructure (R8 confirmed latency-bound:
// MfmaUtil 32%, wall 209 vs 75 us MFMA floor, neither pipe saturated,
// 2 waves/SIMD at 252 regs).
//   - wave tile 64x128 -> 64x64 (acc 128 -> 64 AGPR), block 128x128,
//     4 waves 2x2. Peak regs ~170 -> 3 waves/SIMD = 12 waves/CU (+50%).
//     __launch_bounds__(256,3) enforces.
//   - LDS 32 KB/block x 3 blocks = 96 KB.
//   - 16 (x,z) pairs now; pr = wg&15 with z in LOW bits so the two blocks
//     sharing an XCD (pr, pr+8) have the SAME z, different x -> they read
//     the SAME H columns (L2-shared) while W slices stay 2.36 MB/XCD.
//   - B pipeline within step: bv0 at head, bv1 issued before MFMA half0;
//     genTile covers bv1 latency. (Cross-step B prefetch dropped: register
//     budget.)
// Arithmetic bit-identical to R6/R7/R8 (absmax 0.0625).
// ---------------------------------------------------------------------------
template <int I, int ATOMIC, int NX, int NZ>
__global__ __launch_bounds__(256, 3) void gemm_kan(const float* __restrict__ H,
                                                   const f16* __restrict__ W,
                                                   float* __restrict__ C,
                                                   int N) {
  constexpr int K = 9 * I;
  constexpr int KB = 8 * I;                   // spline/base boundary (mult 64)
  constexpr int K32 = K / 32;
  constexpr int KSTEP = 64 * NZ;              // strided split-K step
  constexpr int NSTEP = K / KSTEP;
  constexpr int NPAIR = NX * NZ;              // 16 in both layers
  __shared__ __align__(16) f16 sA[2 * 128 * 64];  // 32 KB double-buffered
  const int t = threadIdx.x;
  const int wg = blockIdx.x;
  const int pr = wg & (NPAIR - 1);            // (x,z) pair; z in low bits
  const int z  = pr & (NZ - 1);
  const int n0 = (pr / NZ) * 128;
  const int m0 = (wg / NPAIR) * 128;
  const int kBeg = z * 64;
  const int w = t >> 6, lane = t & 63;
  const int wm = (w >> 1) * 64, wn = (w & 1) * 64;
  const int lr = lane & 15, lq = lane >> 4;
  const int srow = t >> 3;                    // staging row 0..31 (q adds 32)
  const int j_ = t & 7;                       // chunk col 0..7
  const int js = j_ ^ (srow & 7);             // swizzled chunk col

  f32x4 acc[4][4] = {};
  const float* Hrow = H + (size_t)(m0 + srow) * I;

  float hs[4];

  // Generate the 128x64 A-tile for k-range [kg, kg+64) into buffer wb.
  // Spline region uses hs[] (prefetched for kg) and re-prefetches for
  // kg+KSTEP (guard kn<KB covers both the silu region and loop end).
  auto genTile = [&](int kg, f16* wb) {
    if (kg < KB) {
#pragma unroll
      for (int q = 0; q < 4; ++q)
        *(f16x8*)&wb[((q * 32 + srow) * 8 + js) * 8] = spline8(hs[q]);
      const int kn = kg + KSTEP;
      if (kn < KB) {
        const int i0n = kn >> 3;
#pragma unroll
        for (int q = 0; q < 4; ++q)
          hs[q] = Hrow[(size_t)(q * 32) * I + i0n + j_];
      }
    } else {
      const int c0 = (kg - KB) + j_ * 8;      // 8 consecutive silu inputs
      f32x4 ha[4][2];
#pragma unroll
      for (int q = 0; q < 4; ++q) {
        const f32x4* p = (const f32x4*)(Hrow + (size_t)(q * 32) * I + c0);
        ha[q][0] = p[0];
        ha[q][1] = p[1];
      }
#pragma unroll
      for (int q = 0; q < 4; ++q) {
        f16x8 o;
#pragma unroll
        for (int s = 0; s < 8; ++s) {
          float h = ha[q][s >> 2][s & 3];
          o[s] = (f16)(h / (1.f + __expf(-h)));
        }
        *(f16x8*)&wb[((q * 32 + srow) * 8 + js) * 8] = o;
      }
    }
  };

  // prologue: prefetch H, generate first tile into buffer 0
  if (kBeg < KB) {
    const int i0 = kBeg >> 3;
#pragma unroll
    for (int q = 0; q < 4; ++q)
      hs[q] = Hrow[(size_t)(q * 32) * I + i0 + j_];
  }
  // wave's fragment-tiled W pointer at current k-step (advances by KSTEP)
  const f16* pk = W + ((size_t)((n0 + wn) >> 4) * K32 + (kBeg >> 5)) * 512 +
                  lane * 8;
  genTile(kBeg, sA);                          // also prefetches hs for next
  __syncthreads();

  int cur = 0;
  for (int s = 0; s < NSTEP; ++s) {
    const f16* rb = sA + cur * (128 * 64);
    f16* wb = sA + (cur ^ 1) * (128 * 64);

    // B frags kk=0: latency covered by av0 ds_reads (+ prior barrier slack)
    f16x8 bv0[4];
#pragma unroll
    for (int j = 0; j < 4; ++j)
      bv0[j] = *(const f16x8*)(pk + (size_t)j * K32 * 512);

    // av half 0 from LDS
    f16x8 av[4];
#pragma unroll
    for (int i = 0; i < 4; ++i) {
      const int ra = wm + i * 16 + lr;
      const int ca = lq ^ (ra & 7);
      av[i] = *(const f16x8*)&rb[ra * 64 + ca * 8];
    }

    // B frags kk=32: latency hides under MFMA half0 + genTile
    f16x8 bv1[4];
#pragma unroll
    for (int j = 0; j < 4; ++j)
      bv1[j] = *(const f16x8*)(pk + (size_t)j * K32 * 512 + 512);

    __builtin_amdgcn_s_setprio(1);
#pragma unroll
    for (int i = 0; i < 4; ++i)
#pragma unroll
      for (int j = 0; j < 4; ++j)
        acc[i][j] = __builtin_amdgcn_mfma_f32_16x16x32_f16(av[i], bv0[j],
                                                           acc[i][j], 0, 0, 0);
    __builtin_amdgcn_s_setprio(0);

    // av half 1
#pragma unroll
    for (int i = 0; i < 4; ++i) {
      const int ra = wm + i * 16 + lr;
      const int ca = (4 + lq) ^ (ra & 7);
      av[i] = *(const f16x8*)&rb[ra * 64 + ca * 8];
    }

    // Generate NEXT tile into the other buffer (independent of MFMA).
    if (s + 1 < NSTEP) genTile(kBeg + (s + 1) * KSTEP, wb);
    pk += (size_t)(KSTEP / 32) * 512;

    __builtin_amdgcn_s_setprio(1);
#pragma unroll
    for (int i = 0; i < 4; ++i)
#pragma unroll
      for (int j = 0; j < 4; ++j)
        acc[i][j] = __builtin_amdgcn_mfma_f32_16x16x32_f16(av[i], bv1[j],
                                                           acc[i][j], 0, 0, 0);
    __builtin_amdgcn_s_setprio(0);

    __syncthreads();   // wb visible, rb reusable
    cur ^= 1;
  }

#pragma unroll
  for (int i = 0; i < 4; ++i) {
#pragma unroll
    for (int j = 0; j < 4; ++j) {
      const int col = n0 + wn + j * 16 + lr;
#pragma unroll
      for (int r = 0; r < 4; ++r) {
        const int row = m0 + wm + i * 16 + lq * 4 + r;
        if (ATOMIC)
          atomicAdd(&C[(size_t)row * N + col], acc[i][j][r]);
        else
          C[(size_t)row * N + col] = acc[i][j][r];
      }
    }
  }
}

// ---------------------------------------------------------------------------
extern "C" void kernel_launch(void* const* d_in, const int* in_sizes, int n_in,
                              void* d_out, int out_size, void* d_ws,
                              size_t ws_size, hipStream_t stream) {
  const float* x     = (const float*)d_in[0];
  const float* coef1 = (const float*)d_in[1];
  const float* sb1   = (const float*)d_in[2];
  const float* ssp1  = (const float*)d_in[3];
  const float* coef2 = (const float*)d_in[4];
  const float* sb2   = (const float*)d_in[5];
  const float* ssp2  = (const float*)d_in[6];

  const int Mtot = 8192;
  const int I1 = 512, O1 = 2048, K1 = I1 * 9;   // 4608
  const int I2 = 2048, O2 = 512, K2 = I2 * 9;   // 18432

  char* ws = (char*)d_ws;
  const size_t szW1 = (size_t)O1 * K1 * sizeof(f16);     // 18.9 MB
  const size_t szW2 = (size_t)O2 * K2 * sizeof(f16);     // 18.9 MB
  const size_t szH  = (size_t)Mtot * O1 * sizeof(float); // 67.1 MB
  if (ws_size < szW1 + szW2 + szH) return;  // cannot run; fail visibly
  f16*   W1 = (f16*)ws;
  f16*   W2 = (f16*)(ws + szW1);
  float* h1 = (float*)(ws + szW1 + szW2);

  // weight prep (fragment-tiled layout)
  {
    int n1 = I1 * O1;
    prep_coef<512, 2048><<<(n1 + 255) / 256, 256, 0, stream>>>(coef1, ssp1, W1);
    prep_base<512, 2048><<<(n1 / 8 + 255) / 256, 256, 0, stream>>>(sb1, W1);
    int n2 = I2 * O2;
    prep_coef<2048, 512><<<(n2 + 255) / 256, 256, 0, stream>>>(coef2, ssp2, W2);
    prep_base<2048, 512><<<(n2 / 8 + 255) / 256, 256, 0, stream>>>(sb2, W2);
  }

  // layer 1: h1 = KanAct(x) @ W1^T — 16 x-tiles x 64 m-tiles = 1024 blocks
  gemm_kan<512, 0, 16, 1><<<dim3(1024), 256, 0, stream>>>(x, W1, h1, O1);

  // layer 2: out = KanAct(h1) @ W2^T — 4 x-tiles x 4 z x 64 m = 1024 blocks
  (void)hipMemsetAsync(d_out, 0, (size_t)Mtot * O2 * sizeof(float), stream);
  gemm_kan<2048, 1, 4, 4><<<dim3(1024), 256, 0, stream>>>(h1, W2,
                                                          (float*)d_out, O2);
}

// Round 4
// 507.205 us; speedup vs baseline: 1.2914x; 1.2914x over previous
//
#include <hip/hip_runtime.h>
#include <cstdint>
#include <cstddef>

typedef _Float16 f16;
typedef _Float16 f16x8 __attribute__((ext_vector_type(8)));
typedef float f32x4 __attribute__((ext_vector_type(4)));

// ---------------------------------------------------------------------------
// W is stored fragment-tiled for mfma_f32_16x16x32_f16's B operand:
// lane l of a wave holds B[n = nf*16 + (l&15)][k = kb*32 + (l>>4)*8 + j].
// Element (n,k) lives at flat f16 index
//   ((n>>4)*(K/32) + (k>>5))*512 + (((k>>3)&3)*16 + (n&15))*8 + (k&7)
// so a wave loads one fragment as ONE coalesced global_load_dwordx4.
// ---------------------------------------------------------------------------

// Wt tile for coef: k = i*8+g  ->  kb=i>>2, lane=(i&3)*16+(o&15), elem g
template <int I, int O>
__global__ void prep_coef(const float* __restrict__ coef,
                          const float* __restrict__ ssp,
                          f16* __restrict__ Wt) {
  constexpr int K32 = (9 * I) / 32;
  int tid = blockIdx.x * 256 + threadIdx.x;
  if (tid >= I * O) return;
  int i = tid / O, o = tid % O;             // o fastest -> coalesced coef reads
  float s = ssp[tid];
  const float* c = coef + (size_t)tid * 8;
  f16x8 out;
#pragma unroll
  for (int g = 0; g < 8; ++g) out[g] = (f16)(c[g] * s);
  size_t addr = ((size_t)(o >> 4) * K32 + (i >> 2)) * 512 +
                (size_t)(((i & 3) * 16) + (o & 15)) * 8;
  *(f16x8*)(Wt + addr) = out;
}

// Wt tile for base: k = 8I+i -> kb=I/4+(i>>5), lane=((i>>3)&3)*16+(o&15), elem i&7
template <int I, int O>
__global__ void prep_base(const float* __restrict__ sb, f16* __restrict__ Wt) {
  constexpr int K32 = (9 * I) / 32;
  int tid = blockIdx.x * 256 + threadIdx.x;
  if (tid >= (I / 8) * O) return;
  int i8 = tid / O, o = tid % O;            // o fastest -> coalesced writes
  f16x8 out;
#pragma unroll
  for (int s = 0; s < 8; ++s)
    out[s] = (f16)sb[(size_t)(i8 * 8 + s) * O + o];
  size_t addr = ((size_t)(o >> 4) * K32 + (I / 4) + (i8 >> 2)) * 512 +
                (size_t)(((i8 & 3) * 16) + (o & 15)) * 8;
  *(f16x8*)(Wt + addr) = out;
}

// ---------------------------------------------------------------------------
// 8-slot cubic B-spline basis, packed-shift form (verified R6, absmax 0.0625).
// ---------------------------------------------------------------------------
__device__ __forceinline__ f16x8 spline8(float h) {
  float v = __builtin_fmaf(2.5f, h, 5.5f);
  float c = floorf(v);
  float f = v - c;
  float f2 = f * f, f3 = f2 * f;
  float b3 = f3 * (1.f / 6.f);
  float t = 1.f - f;
  float b0 = t * t * t * (1.f / 6.f);
  float b1 = (2.f / 3.f) - f2 + 0.5f * f3;
  float b2 = 1.f - b0 - b1 - b3;
  unsigned int u01 =
      __builtin_bit_cast(unsigned int, __builtin_amdgcn_cvt_pkrtz(b0, b1));
  unsigned int u23 =
      __builtin_bit_cast(unsigned int, __builtin_amdgcn_cvt_pkrtz(b2, b3));
  unsigned long long pk = (unsigned long long)u01 |
                          ((unsigned long long)u23 << 32);
  int ci = (int)c;
  int s = (ci - 3) * 16;                // bit offset of slot c-3
  __uint128_t r = 0;
  if (s >= 0) {
    if (s < 128) r = (__uint128_t)pk << s;
  } else {
    int q = -s;
    if (q < 64) r = (__uint128_t)(pk >> q);
  }
  return __builtin_bit_cast(f16x8, r);
}

// ---------------------------------------------------------------------------
// Fused KAN GEMM. R10: PRODUCER/CONSUMER WAVE SPECIALIZATION.
// R9 falsified occupancy-via-smaller-tiles (MfmaUtil 32->21: doubled per-CU
// A-gen + B-loads swamped the extra waves). R8 analysis: MFMA busy 2560 +
// VALU busy ~2500 of 6967 cyc/step/SIMD -- the pipes are separate but one
// instruction stream alternates phases, so overlap is accidental.
//
// Block = 512 threads. Waves 0-3 = CONSUMERS: R8's exact 64x128 MFMA tile
// (block 128x256), B register pipeline, no A-gen. Waves 4-7 = PRODUCERS:
// R8's exact genTile (spline/silu -> swizzled LDS), no MFMA. Wave i lands
// on SIMD i%4 -> each SIMD hosts 1 consumer (252 regs) + 1 producer:
// MFMA pipe fed continuously while producer VALU runs beside it. setprio
// (T5) now has real role diversity to arbitrate. Same dbuf + 1 barrier per
// K-step on BOTH paths (equal barrier counts). 1 block/CU; 512 blocks =
// exactly 2 rounds. XCD pinning: 8 (x,z) pairs, W slice 2.36 MB/XCD.
// Arithmetic bit-identical to R6-R9 (absmax 0.0625).
// ---------------------------------------------------------------------------
template <int I, int ATOMIC, int NX, int NZ>
__global__ __launch_bounds__(512, 2) void gemm_kan(const float* __restrict__ H,
                                                   const f16* __restrict__ W,
                                                   float* __restrict__ C,
                                                   int N) {
  constexpr int K = 9 * I;
  constexpr int KB = 8 * I;                   // spline/base boundary (mult 64)
  constexpr int K32 = K / 32;
  constexpr int KSTEP = 64 * NZ;              // strided split-K step
  constexpr int NSTEP = K / KSTEP;
  constexpr int NPAIR = NX * NZ;              // 8 in both layers
  __shared__ __align__(16) f16 sA[2 * 128 * 64];  // 32 KB double-buffered
  const int t = threadIdx.x;
  const int wg = blockIdx.x;
  const int pr = wg & (NPAIR - 1);            // (x,z) pair; wgid%8 == XCD
  const int n0 = (pr % NX) * 256;
  const int m0 = (wg / NPAIR) * 128;
  const int kBeg = (pr / NX) * 64;

  int cur = 0;

  if (t >= 256) {
    // ------------------------------ PRODUCER ------------------------------
    const int tp = t - 256;
    const int srow = tp >> 3;                 // staging row 0..31 (q adds 32)
    const int j_ = tp & 7;                    // chunk col 0..7
    const int js = j_ ^ (srow & 7);           // swizzled chunk col
    const float* Hrow = H + (size_t)(m0 + srow) * I;
    float hs[4];

    auto genTile = [&](int kg, f16* wb) {
      if (kg < KB) {
#pragma unroll
        for (int q = 0; q < 4; ++q)
          *(f16x8*)&wb[((q * 32 + srow) * 8 + js) * 8] = spline8(hs[q]);
        const int kn = kg + KSTEP;
        if (kn < KB) {
          const int i0n = kn >> 3;
#pragma unroll
          for (int q = 0; q < 4; ++q)
            hs[q] = Hrow[(size_t)(q * 32) * I + i0n + j_];
        }
      } else {
        const int c0 = (kg - KB) + j_ * 8;    // 8 consecutive silu inputs
        f32x4 ha[4][2];
#pragma unroll
        for (int q = 0; q < 4; ++q) {
          const f32x4* p = (const f32x4*)(Hrow + (size_t)(q * 32) * I + c0);
          ha[q][0] = p[0];
          ha[q][1] = p[1];
        }
#pragma unroll
        for (int q = 0; q < 4; ++q) {
          f16x8 o;
#pragma unroll
          for (int s = 0; s < 8; ++s) {
            float h = ha[q][s >> 2][s & 3];
            o[s] = (f16)(h / (1.f + __expf(-h)));
          }
          *(f16x8*)&wb[((q * 32 + srow) * 8 + js) * 8] = o;
        }
      }
    };

    if (kBeg < KB) {
      const int i0 = kBeg >> 3;
#pragma unroll
      for (int q = 0; q < 4; ++q)
        hs[q] = Hrow[(size_t)(q * 32) * I + i0 + j_];
    }
    genTile(kBeg, sA);                        // tile for step 0 into buf 0
    __syncthreads();

    for (int s = 0; s < NSTEP; ++s) {
      f16* wb = sA + (cur ^ 1) * (128 * 64);
      if (s + 1 < NSTEP) genTile(kBeg + (s + 1) * KSTEP, wb);
      __syncthreads();                        // matches consumer barrier
      cur ^= 1;
    }
    return;                                   // no epilogue for producers
  }

  // ------------------------------- CONSUMER -------------------------------
  const int w = t >> 6, lane = t & 63;
  const int wm = (w >> 1) * 64, wn = (w & 1) * 128;
  const int lr = lane & 15, lq = lane >> 4;

  f32x4 acc[4][8] = {};
  // wave's fragment-tiled W pointer at current k-step (advances by KSTEP)
  const f16* pk = W + ((size_t)((n0 + wn) >> 4) * K32 + (kBeg >> 5)) * 512 +
                  lane * 8;
  f16x8 bvA[8];
#pragma unroll
  for (int j = 0; j < 8; ++j)
    bvA[j] = *(const f16x8*)(pk + (size_t)j * K32 * 512);
  __syncthreads();                            // wait for producer tile 0

  for (int s = 0; s < NSTEP; ++s) {
    const f16* rb = sA + cur * (128 * 64);

    // B frags kk=32 of THIS step: latency hides under av0 reads + MFMA0.
    f16x8 bvB[8];
#pragma unroll
    for (int j = 0; j < 8; ++j)
      bvB[j] = *(const f16x8*)(pk + (size_t)j * K32 * 512 + 512);

    // av half 0 from LDS
    f16x8 av[4];
#pragma unroll
    for (int i = 0; i < 4; ++i) {
      const int ra = wm + i * 16 + lr;
      const int ca = lq ^ (ra & 7);
      av[i] = *(const f16x8*)&rb[ra * 64 + ca * 8];
    }

    __builtin_amdgcn_s_setprio(1);
#pragma unroll
    for (int i = 0; i < 4; ++i)
#pragma unroll
      for (int j = 0; j < 8; ++j)
        acc[i][j] = __builtin_amdgcn_mfma_f32_16x16x32_f16(av[i], bvA[j],
                                                           acc[i][j], 0, 0, 0);
    __builtin_amdgcn_s_setprio(0);

    // av half 1
#pragma unroll
    for (int i = 0; i < 4; ++i) {
      const int ra = wm + i * 16 + lr;
      const int ca = (4 + lq) ^ (ra & 7);
      av[i] = *(const f16x8*)&rb[ra * 64 + ca * 8];
    }

    // NEXT step's bv(kk=0): latency hides under MFMA half1 + barrier.
    pk += (size_t)(KSTEP / 32) * 512;
    if (s + 1 < NSTEP) {
#pragma unroll
      for (int j = 0; j < 8; ++j)
        bvA[j] = *(const f16x8*)(pk + (size_t)j * K32 * 512);
    }

    __builtin_amdgcn_s_setprio(1);
#pragma unroll
    for (int i = 0; i < 4; ++i)
#pragma unroll
      for (int j = 0; j < 8; ++j)
        acc[i][j] = __builtin_amdgcn_mfma_f32_16x16x32_f16(av[i], bvB[j],
                                                           acc[i][j], 0, 0, 0);
    __builtin_amdgcn_s_setprio(0);

    __syncthreads();                          // next tile ready, rb reusable
    cur ^= 1;
  }

#pragma unroll
  for (int i = 0; i < 4; ++i) {
#pragma unroll
    for (int j = 0; j < 8; ++j) {
      const int col = n0 + wn + j * 16 + lr;
#pragma unroll
      for (int r = 0; r < 4; ++r) {
        const int row = m0 + wm + i * 16 + lq * 4 + r;
        if (ATOMIC)
          atomicAdd(&C[(size_t)row * N + col], acc[i][j][r]);
        else
          C[(size_t)row * N + col] = acc[i][j][r];
      }
    }
  }
}

// ---------------------------------------------------------------------------
extern "C" void kernel_launch(void* const* d_in, const int* in_sizes, int n_in,
                              void* d_out, int out_size, void* d_ws,
                              size_t ws_size, hipStream_t stream) {
  const float* x     = (const float*)d_in[0];
  const float* coef1 = (const float*)d_in[1];
  const float* sb1   = (const float*)d_in[2];
  const float* ssp1  = (const float*)d_in[3];
  const float* coef2 = (const float*)d_in[4];
  const float* sb2   = (const float*)d_in[5];
  const float* ssp2  = (const float*)d_in[6];

  const int Mtot = 8192;
  const int I1 = 512, O1 = 2048, K1 = I1 * 9;   // 4608
  const int I2 = 2048, O2 = 512, K2 = I2 * 9;   // 18432

  char* ws = (char*)d_ws;
  const size_t szW1 = (size_t)O1 * K1 * sizeof(f16);     // 18.9 MB
  const size_t szW2 = (size_t)O2 * K2 * sizeof(f16);     // 18.9 MB
  const size_t szH  = (size_t)Mtot * O1 * sizeof(float); // 67.1 MB
  if (ws_size < szW1 + szW2 + szH) return;  // cannot run; fail visibly
  f16*   W1 = (f16*)ws;
  f16*   W2 = (f16*)(ws + szW1);
  float* h1 = (float*)(ws + szW1 + szW2);

  // weight prep (fragment-tiled layout)
  {
    int n1 = I1 * O1;
    prep_coef<512, 2048><<<(n1 + 255) / 256, 256, 0, stream>>>(coef1, ssp1, W1);
    prep_base<512, 2048><<<(n1 / 8 + 255) / 256, 256, 0, stream>>>(sb1, W1);
    int n2 = I2 * O2;
    prep_coef<2048, 512><<<(n2 + 255) / 256, 256, 0, stream>>>(coef2, ssp2, W2);
    prep_base<2048, 512><<<(n2 / 8 + 255) / 256, 256, 0, stream>>>(sb2, W2);
  }

  // layer 1: h1 = KanAct(x) @ W1^T — 8 x-pairs x 64 m = 512 blocks, 512 thr
  gemm_kan<512, 0, 8, 1><<<dim3(512), 512, 0, stream>>>(x, W1, h1, O1);

  // layer 2: out = KanAct(h1) @ W2^T — strided split-K=4, 2x4 pairs x 64 m
  (void)hipMemsetAsync(d_out, 0, (size_t)Mtot * O2 * sizeof(float), stream);
  gemm_kan<2048, 1, 2, 4><<<dim3(512), 512, 0, stream>>>(h1, W2,
                                                         (float*)d_out, O2);
}

// Round 5
// 490.538 us; speedup vs baseline: 1.3353x; 1.0340x over previous
//
#include <hip/hip_runtime.h>
#include <cstdint>
#include <cstddef>

typedef _Float16 f16;
typedef _Float16 f16x8 __attribute__((ext_vector_type(8)));
typedef float f32x4 __attribute__((ext_vector_type(4)));

// Raw workgroup barrier WITHOUT the __syncthreads() full-drain semantics.
// Only lgkmcnt is drained (LDS visibility: my ds_writes complete + my
// ds_reads of the buffer about to be overwritten complete). Global loads
// (B-fragments, H prefetch) stay IN FLIGHT across the barrier and are
// waited with compiler-inserted counted vmcnt(N) at first use (T4, m218).
#define BAR_LDS() asm volatile("s_waitcnt lgkmcnt(0)\n\ts_barrier" ::: "memory")

// ---------------------------------------------------------------------------
// W is stored fragment-tiled for mfma_f32_16x16x32_f16's B operand:
// lane l of a wave holds B[n = nf*16 + (l&15)][k = kb*32 + (l>>4)*8 + j].
// Element (n,k) lives at flat f16 index
//   ((n>>4)*(K/32) + (k>>5))*512 + (((k>>3)&3)*16 + (n&15))*8 + (k&7)
// so a wave loads one fragment as ONE coalesced global_load_dwordx4.
// ---------------------------------------------------------------------------

// Wt tile for coef: k = i*8+g  ->  kb=i>>2, lane=(i&3)*16+(o&15), elem g
template <int I, int O>
__global__ void prep_coef(const float* __restrict__ coef,
                          const float* __restrict__ ssp,
                          f16* __restrict__ Wt) {
  constexpr int K32 = (9 * I) / 32;
  int tid = blockIdx.x * 256 + threadIdx.x;
  if (tid >= I * O) return;
  int i = tid / O, o = tid % O;             // o fastest -> coalesced coef reads
  float s = ssp[tid];
  const float* c = coef + (size_t)tid * 8;
  f16x8 out;
#pragma unroll
  for (int g = 0; g < 8; ++g) out[g] = (f16)(c[g] * s);
  size_t addr = ((size_t)(o >> 4) * K32 + (i >> 2)) * 512 +
                (size_t)(((i & 3) * 16) + (o & 15)) * 8;
  *(f16x8*)(Wt + addr) = out;
}

// Wt tile for base: k = 8I+i -> kb=I/4+(i>>5), lane=((i>>3)&3)*16+(o&15), elem i&7
template <int I, int O>
__global__ void prep_base(const float* __restrict__ sb, f16* __restrict__ Wt) {
  constexpr int K32 = (9 * I) / 32;
  int tid = blockIdx.x * 256 + threadIdx.x;
  if (tid >= (I / 8) * O) return;
  int i8 = tid / O, o = tid % O;            // o fastest -> coalesced writes
  f16x8 out;
#pragma unroll
  for (int s = 0; s < 8; ++s)
    out[s] = (f16)sb[(size_t)(i8 * 8 + s) * O + o];
  size_t addr = ((size_t)(o >> 4) * K32 + (I / 4) + (i8 >> 2)) * 512 +
                (size_t)(((i8 & 3) * 16) + (o & 15)) * 8;
  *(f16x8*)(Wt + addr) = out;
}

// ---------------------------------------------------------------------------
// 8-slot cubic B-spline basis, packed-shift form (verified R6, absmax 0.0625).
// ---------------------------------------------------------------------------
__device__ __forceinline__ f16x8 spline8(float h) {
  float v = __builtin_fmaf(2.5f, h, 5.5f);
  float c = floorf(v);
  float f = v - c;
  float f2 = f * f, f3 = f2 * f;
  float b3 = f3 * (1.f / 6.f);
  float t = 1.f - f;
  float b0 = t * t * t * (1.f / 6.f);
  float b1 = (2.f / 3.f) - f2 + 0.5f * f3;
  float b2 = 1.f - b0 - b1 - b3;
  unsigned int u01 =
      __builtin_bit_cast(unsigned int, __builtin_amdgcn_cvt_pkrtz(b0, b1));
  unsigned int u23 =
      __builtin_bit_cast(unsigned int, __builtin_amdgcn_cvt_pkrtz(b2, b3));
  unsigned long long pk = (unsigned long long)u01 |
                          ((unsigned long long)u23 << 32);
  int ci = (int)c;
  int s = (ci - 3) * 16;                // bit offset of slot c-3
  __uint128_t r = 0;
  if (s >= 0) {
    if (s < 128) r = (__uint128_t)pk << s;
  } else {
    int q = -s;
    if (q < 64) r = (__uint128_t)(pk >> q);
  }
  return __builtin_bit_cast(f16x8, r);
}

// ---------------------------------------------------------------------------
// Fused KAN GEMM, 128(M) x 256(N) tile, BK=64 — R8 structure + R11 barrier.
//
// R11: the ONE change vs R8 is BAR_LDS() replacing __syncthreads(). R7/R9/
// R10 all pinned MfmaUtil at 28-32% because __syncthreads drains
// vmcnt(0) at EVERY K-step barrier (compiler-mandated), killing every
// cross-step prefetch (bvA-next, hs-next) at the barrier it was meant to
// fly across (m97 drain analysis; m233: 2-phase barrier overhead = 72%;
// m218: counted-vmcnt vs drain0 = +38-73%). With the raw barrier + lgkm-
// only drain, B/H loads stay in flight across the barrier and get counted
// vmcnt(N) waits at first use. LDS hazards (producer writes visible;
// reads-before-overwrite) are exactly what lgkmcnt(0)+s_barrier covers.
//
// XCD pinning (R8a): 8 (x,z) pairs == wgid%8 == XCD -> W slice 2.36 MB/XCD
// L2-resident; strided split-K so every z has the same spline/silu mix.
// B register pipeline (R8b): bvB issued at step head (under av0+MFMA0);
// next step's bvA issued after genTile (under MFMA1 + barrier + av0').
// setprio around MFMA clusters (R8c/T5).
// Arithmetic bit-identical to R6-R10 (absmax 0.0625).
// ---------------------------------------------------------------------------
template <int I, int ATOMIC, int NX, int NZ>
__global__ __launch_bounds__(256, 2) void gemm_kan(const float* __restrict__ H,
                                                   const f16* __restrict__ W,
                                                   float* __restrict__ C,
                                                   int N) {
  constexpr int K = 9 * I;
  constexpr int KB = 8 * I;                   // spline/base boundary (mult 64)
  constexpr int K32 = K / 32;
  constexpr int KSTEP = 64 * NZ;              // strided split-K step
  constexpr int NSTEP = K / KSTEP;
  __shared__ __align__(16) f16 sA[2 * 128 * 64];  // 32 KB double-buffered
  const int t = threadIdx.x;
  const int wg = blockIdx.x;
  const int pr = wg & 7;                      // XCD-pair id (wgid%8 == XCD)
  const int n0 = (pr % NX) * 256;
  const int m0 = (wg >> 3) * 128;
  const int kBeg = (pr / NX) * 64;
  const int w = t >> 6, lane = t & 63;
  const int wm = (w >> 1) * 64, wn = (w & 1) * 128;
  const int lr = lane & 15, lq = lane >> 4;
  const int srow = t >> 3;                    // staging row 0..31 (q adds 32)
  const int j_ = t & 7;                       // chunk col 0..7
  const int js = j_ ^ (srow & 7);             // swizzled chunk col

  f32x4 acc[4][8] = {};
  const float* Hrow = H + (size_t)(m0 + srow) * I;

  float hs[4];

  // Generate the 128x64 A-tile for k-range [kg, kg+64) into buffer wb.
  // Spline region uses hs[] (prefetched for kg) and re-prefetches for
  // kg+KSTEP (guard kn<KB covers both the silu region and loop end).
  auto genTile = [&](int kg, f16* wb) {
    if (kg < KB) {
#pragma unroll
      for (int q = 0; q < 4; ++q)
        *(f16x8*)&wb[((q * 32 + srow) * 8 + js) * 8] = spline8(hs[q]);
      const int kn = kg + KSTEP;
      if (kn < KB) {
        const int i0n = kn >> 3;
#pragma unroll
        for (int q = 0; q < 4; ++q)
          hs[q] = Hrow[(size_t)(q * 32) * I + i0n + j_];
      }
    } else {
      const int c0 = (kg - KB) + j_ * 8;      // 8 consecutive silu inputs
      f32x4 ha[4][2];
#pragma unroll
      for (int q = 0; q < 4; ++q) {
        const f32x4* p = (const f32x4*)(Hrow + (size_t)(q * 32) * I + c0);
        ha[q][0] = p[0];
        ha[q][1] = p[1];
      }
#pragma unroll
      for (int q = 0; q < 4; ++q) {
        f16x8 o;
#pragma unroll
        for (int s = 0; s < 8; ++s) {
          float h = ha[q][s >> 2][s & 3];
          o[s] = (f16)(h / (1.f + __expf(-h)));
        }
        *(f16x8*)&wb[((q * 32 + srow) * 8 + js) * 8] = o;
      }
    }
  };

  // prologue: prefetch H, preload first B half (kk=0), generate first tile
  if (kBeg < KB) {
    const int i0 = kBeg >> 3;
#pragma unroll
    for (int q = 0; q < 4; ++q)
      hs[q] = Hrow[(size_t)(q * 32) * I + i0 + j_];
  }
  // wave's fragment-tiled W pointer at current k-step (advances by KSTEP)
  const f16* pk = W + ((size_t)((n0 + wn) >> 4) * K32 + (kBeg >> 5)) * 512 +
                  lane * 8;
  f16x8 bvA[8];
#pragma unroll
  for (int j = 0; j < 8; ++j)
    bvA[j] = *(const f16x8*)(pk + (size_t)j * K32 * 512);
  genTile(kBeg, sA);                          // also prefetches hs for next
  BAR_LDS();

  int cur = 0;
  for (int s = 0; s < NSTEP; ++s) {
    const f16* rb = sA + cur * (128 * 64);
    f16* wb = sA + (cur ^ 1) * (128 * 64);

    // B frags for kk=32 of THIS step: latency hides under av0 + MFMA half0.
    f16x8 bvB[8];
#pragma unroll
    for (int j = 0; j < 8; ++j)
      bvB[j] = *(const f16x8*)(pk + (size_t)j * K32 * 512 + 512);

    // av half 0 from LDS
    f16x8 av[4];
#pragma unroll
    for (int i = 0; i < 4; ++i) {
      const int ra = wm + i * 16 + lr;
      const int ca = lq ^ (ra & 7);
      av[i] = *(const f16x8*)&rb[ra * 64 + ca * 8];
    }

    __builtin_amdgcn_s_setprio(1);
#pragma unroll
    for (int i = 0; i < 4; ++i)
#pragma unroll
      for (int j = 0; j < 8; ++j)
        acc[i][j] = __builtin_amdgcn_mfma_f32_16x16x32_f16(av[i], bvA[j],
                                                           acc[i][j], 0, 0, 0);
    __builtin_amdgcn_s_setprio(0);

    // av half 1
#pragma unroll
    for (int i = 0; i < 4; ++i) {
      const int ra = wm + i * 16 + lr;
      const int ca = (4 + lq) ^ (ra & 7);
      av[i] = *(const f16x8*)&rb[ra * 64 + ca * 8];
    }

    // Generate NEXT tile into the other buffer (independent of MFMA).
    const bool more = (s + 1 < NSTEP);
    if (more) genTile(kBeg + (s + 1) * KSTEP, wb);

    // NEXT step's bv(kk=0): stays in flight across the raw barrier now.
    pk += (size_t)(KSTEP / 32) * 512;
    if (more) {
#pragma unroll
      for (int j = 0; j < 8; ++j)
        bvA[j] = *(const f16x8*)(pk + (size_t)j * K32 * 512);
    }

    __builtin_amdgcn_s_setprio(1);
#pragma unroll
    for (int i = 0; i < 4; ++i)
#pragma unroll
      for (int j = 0; j < 8; ++j)
        acc[i][j] = __builtin_amdgcn_mfma_f32_16x16x32_f16(av[i], bvB[j],
                                                           acc[i][j], 0, 0, 0);
    __builtin_amdgcn_s_setprio(0);

    BAR_LDS();         // lgkm-only drain: wb visible, rb safely reusable
    cur ^= 1;
  }

#pragma unroll
  for (int i = 0; i < 4; ++i) {
#pragma unroll
    for (int j = 0; j < 8; ++j) {
      const int col = n0 + wn + j * 16 + lr;
#pragma unroll
      for (int r = 0; r < 4; ++r) {
        const int row = m0 + wm + i * 16 + lq * 4 + r;
        if (ATOMIC)
          atomicAdd(&C[(size_t)row * N + col], acc[i][j][r]);
        else
          C[(size_t)row * N + col] = acc[i][j][r];
      }
    }
  }
}

// ---------------------------------------------------------------------------
extern "C" void kernel_launch(void* const* d_in, const int* in_sizes, int n_in,
                              void* d_out, int out_size, void* d_ws,
                              size_t ws_size, hipStream_t stream) {
  const float* x     = (const float*)d_in[0];
  const float* coef1 = (const float*)d_in[1];
  const float* sb1   = (const float*)d_in[2];
  const float* ssp1  = (const float*)d_in[3];
  const float* coef2 = (const float*)d_in[4];
  const float* sb2   = (const float*)d_in[5];
  const float* ssp2  = (const float*)d_in[6];

  const int Mtot = 8192;
  const int I1 = 512, O1 = 2048, K1 = I1 * 9;   // 4608
  const int I2 = 2048, O2 = 512, K2 = I2 * 9;   // 18432

  char* ws = (char*)d_ws;
  const size_t szW1 = (size_t)O1 * K1 * sizeof(f16);     // 18.9 MB
  const size_t szW2 = (size_t)O2 * K2 * sizeof(f16);     // 18.9 MB
  const size_t szH  = (size_t)Mtot * O1 * sizeof(float); // 67.1 MB
  if (ws_size < szW1 + szW2 + szH) return;  // cannot run; fail visibly
  f16*   W1 = (f16*)ws;
  f16*   W2 = (f16*)(ws + szW1);
  float* h1 = (float*)(ws + szW1 + szW2);

  // weight prep (fragment-tiled layout)
  {
    int n1 = I1 * O1;
    prep_coef<512, 2048><<<(n1 + 255) / 256, 256, 0, stream>>>(coef1, ssp1, W1);
    prep_base<512, 2048><<<(n1 / 8 + 255) / 256, 256, 0, stream>>>(sb1, W1);
    int n2 = I2 * O2;
    prep_coef<2048, 512><<<(n2 + 255) / 256, 256, 0, stream>>>(coef2, ssp2, W2);
    prep_base<2048, 512><<<(n2 / 8 + 255) / 256, 256, 0, stream>>>(sb2, W2);
  }

  // layer 1: h1 = KanAct(x) @ W1^T — 512 blocks, pair=(x), 2/CU.
  gemm_kan<512, 0, 8, 1><<<dim3(512), 256, 0, stream>>>(x, W1, h1, O1);

  // layer 2: out = KanAct(h1) @ W2^T — strided split-K=4, pair=(x,z).
  (void)hipMemsetAsync(d_out, 0, (size_t)Mtot * O2 * sizeof(float), stream);
  gemm_kan<2048, 1, 2, 4><<<dim3(512), 256, 0, stream>>>(h1, W2,
                                                         (float*)d_out, O2);
}